// Round 2
// baseline (309.111 us; speedup 1.0000x reference)
//
#include <hip/hip_runtime.h>
#include <stdint.h>

#define NAC 147456   // 128*128*9
#define NGT 64
#define NB  8

// ---------------- Threefry-2x32 (JAX-compatible, 20 rounds) ----------------
__host__ __device__ static inline uint32_t tf_rotl(uint32_t x, uint32_t d) {
  return (x << d) | (x >> (32u - d));
}

__host__ __device__ static inline void threefry2x32(
    uint32_t k0, uint32_t k1, uint32_t x0, uint32_t x1,
    uint32_t* o0, uint32_t* o1)
{
  const uint32_t ks2 = k0 ^ k1 ^ 0x1BD11BDAu;
  x0 += k0; x1 += k1;
#define TFR(r) { x0 += x1; x1 = tf_rotl(x1, (r)); x1 ^= x0; }
  TFR(13u) TFR(15u) TFR(26u) TFR(6u)   x0 += k1;  x1 += ks2 + 1u;
  TFR(17u) TFR(29u) TFR(16u) TFR(24u)  x0 += ks2; x1 += k0 + 2u;
  TFR(13u) TFR(15u) TFR(26u) TFR(6u)   x0 += k0;  x1 += k1 + 3u;
  TFR(17u) TFR(29u) TFR(16u) TFR(24u)  x0 += k1;  x1 += ks2 + 4u;
  TFR(13u) TFR(15u) TFR(26u) TFR(6u)   x0 += ks2; x1 += k0 + 5u;
#undef TFR
  *o0 = x0; *o1 = x1;
}

// ---------------- Kernel 1: IoU argmax + proposals + pos count ----------------
// One thread per (b, anchor). Writes out[...,0:4] = delta2bbox(anchor, delta),
// out[...,4] = pos ? best_idx+1 : 0, out[...,5:7] = 0 (k2 rewrites 4:8).
// Accumulates n_pos per batch into counts[b] (one atomic per wave).
__global__ __launch_bounds__(256) void k1_classify(
    const float* __restrict__ anchors,
    const float* __restrict__ gt,
    const float* __restrict__ deltas,
    float* __restrict__ out,
    int* __restrict__ counts)
{
  __shared__ float gb[NGT][4];
  __shared__ float garea[NGT];
  const int b   = blockIdx.y;
  const int tid = threadIdx.x;

  if (tid < NGT) {
    float4 g = *reinterpret_cast<const float4*>(gt + ((size_t)b * NGT + tid) * 4);
    gb[tid][0] = g.x; gb[tid][1] = g.y; gb[tid][2] = g.z; gb[tid][3] = g.w;
    garea[tid] = fmaxf(g.z - g.x, 0.0f) * fmaxf(g.w - g.y, 0.0f);
  }
  __syncthreads();

  const int i = blockIdx.x * 256 + tid;

  const float4 a = *reinterpret_cast<const float4*>(anchors + (size_t)i * 4);
  const float a0 = a.x, a1 = a.y, a2 = a.z, a3 = a.w;
  const float area_a = fmaxf(a2 - a0, 0.0f) * fmaxf(a3 - a1, 0.0f);

  // IoU argmax over 64 gt boxes; expression is FMA-contraction-free =>
  // bit-identical decisions vs fp32 numpy reference.
  float best = -1.0f;
  int   bidx = 0;
#pragma unroll 8
  for (int j = 0; j < NGT; ++j) {
    float yi = fmaxf(a0, gb[j][0]);
    float xi = fmaxf(a1, gb[j][1]);
    float ya = fminf(a2, gb[j][2]);
    float xa = fminf(a3, gb[j][3]);
    float inter = fmaxf(ya - yi, 0.0f) * fmaxf(xa - xi, 0.0f);
    float uni   = area_a + garea[j] - inter;
    float iou   = (10000.0f * inter) / (uni + 1e-5f);
    if (iou > best) { best = iou; bidx = j; }  // first-max == jnp.argmax
  }
  const bool pos = best > 5000.0f;

  // proposals = delta2bbox(anchor, delta)
  const float4 d = *reinterpret_cast<const float4*>(deltas + ((size_t)b * NAC + i) * 4);
  const float wb = a3 - a1, hb = a2 - a0;
  const float xc = a1 + 0.5f * wb + wb * d.x;
  const float yc = a0 + 0.5f * hb + hb * d.y;
  const float w_ = wb * expf(d.z);
  const float h_ = hb * expf(d.w);

  float* rowp = out + ((size_t)b * NAC + i) * 8;
  float4 p0 = make_float4(yc - 0.5f * h_, xc - 0.5f * w_,
                          yc + 0.5f * h_, xc + 0.5f * w_);
  float4 p1 = make_float4(pos ? (float)(bidx + 1) : 0.0f, 0.0f, 0.0f, 0.0f);
  *reinterpret_cast<float4*>(rowp)     = p0;
  *reinterpret_cast<float4*>(rowp + 4) = p1;

  unsigned long long m = __ballot(pos);
  if ((tid & 63) == 0)
    atomicAdd(&counts[b], (int)__popcll(m));
}

// ---------------- Kernel 2: threefry sampling + bbox2delta targets ----------------
// One thread per flat row f = b*NAC + i.  Partitionable-threefry bits:
// bits[f] = o0^o1 of threefry(kp, hi=0, lo=f); u = bitcast((bits>>9)|0x3F800000)-1.
__global__ __launch_bounds__(256) void k2_sample(
    const float* __restrict__ anchors,
    const float* __restrict__ gt,
    float* __restrict__ out,
    const int* __restrict__ counts,
    uint32_t kp0, uint32_t kp1)
{
  const int f = blockIdx.x * 256 + threadIdx.x;
  const int b = f / NAC;
  const int i = f - b * NAC;
  float* rowp = out + (size_t)f * 8;

  const float flag = rowp[4];
  const float th   = 128.0f / ((float)counts[b] + 1e-6f);

  uint32_t o0, o1;
  threefry2x32(kp0, kp1, 0u, (uint32_t)f, &o0, &o1);
  const uint32_t bits = o0 ^ o1;
  union { uint32_t u; float fl; } cv;
  cv.u = (bits >> 9) | 0x3F800000u;
  const float rnd = cv.fl - 1.0f;

  float4 r = make_float4(0.0f, 0.0f, 0.0f, 0.0f);
  if (flag > 0.0f && rnd < th) {
    const int j = (int)flag - 1;
    const float4 a = *reinterpret_cast<const float4*>(anchors + (size_t)i * 4);
    const float4 g = *reinterpret_cast<const float4*>(gt + ((size_t)b * NGT + j) * 4);

    const float wr  = a.w - a.y,          hr  = a.z - a.x;
    const float xcr = a.y + 0.5f * wr,    ycr = a.x + 0.5f * hr;
    const float wrc = fmaxf(wr, 1e-5f),   hrc = fmaxf(hr, 1e-5f);
    const float wl  = g.w - g.y,          hl  = g.z - g.x;
    const float xcl = g.y + 0.5f * wl,    ycl = g.x + 0.5f * hl;

    r.x = fminf(fmaxf((xcl - xcr) / wrc, -10.0f), 10.0f);
    r.y = fminf(fmaxf((ycl - ycr) / hrc, -10.0f), 10.0f);
    r.z = fminf(fmaxf(logf(wl / wrc),    -10.0f), 10.0f);
    r.w = fminf(fmaxf(logf(hl / hrc),    -10.0f), 10.0f);
  }

  *reinterpret_cast<float4*>(rowp + 4) = r;
}

extern "C" void kernel_launch(void* const* d_in, const int* in_sizes, int n_in,
                              void* d_out, int out_size, void* d_ws, size_t ws_size,
                              hipStream_t stream)
{
  const float* anchors = (const float*)d_in[0];
  const float* gt      = (const float*)d_in[1];
  const float* deltas  = (const float*)d_in[2];
  float* out  = (float*)d_out;
  int* counts = (int*)d_ws;

  hipMemsetAsync(counts, 0, NB * sizeof(int), stream);

  // kp = jax.random.split(jax.random.key(42))[0] under threefry_partitionable
  // (JAX >= 0.5 default): kp = threefry2x32((0,42), hi=0, lo=0), full pair.
  uint32_t kp0, kp1;
  threefry2x32(0u, 42u, 0u, 0u, &kp0, &kp1);

  dim3 g1(NAC / 256, NB);
  k1_classify<<<g1, dim3(256), 0, stream>>>(anchors, gt, deltas, out, counts);

  const int total = NB * NAC;
  k2_sample<<<total / 256, 256, 0, stream>>>(anchors, gt, out, counts, kp0, kp1);
}

// Round 3
// 157.323 us; speedup vs baseline: 1.9648x; 1.9648x over previous
//
#include <hip/hip_runtime.h>
#include <stdint.h>

#define NAC 147456   // 128*128*9
#define NGT 64
#define NB  8
#define APT 4        // anchors per thread in k1
#define K1B 256      // k1 block size

// ---------------- Threefry-2x32 (JAX-compatible, 20 rounds) ----------------
__host__ __device__ static inline uint32_t tf_rotl(uint32_t x, uint32_t d) {
  return (x << d) | (x >> (32u - d));
}

__host__ __device__ static inline void threefry2x32(
    uint32_t k0, uint32_t k1, uint32_t x0, uint32_t x1,
    uint32_t* o0, uint32_t* o1)
{
  const uint32_t ks2 = k0 ^ k1 ^ 0x1BD11BDAu;
  x0 += k0; x1 += k1;
#define TFR(r) { x0 += x1; x1 = tf_rotl(x1, (r)); x1 ^= x0; }
  TFR(13u) TFR(15u) TFR(26u) TFR(6u)   x0 += k1;  x1 += ks2 + 1u;
  TFR(17u) TFR(29u) TFR(16u) TFR(24u)  x0 += ks2; x1 += k0 + 2u;
  TFR(13u) TFR(15u) TFR(26u) TFR(6u)   x0 += k0;  x1 += k1 + 3u;
  TFR(17u) TFR(29u) TFR(16u) TFR(24u)  x0 += k1;  x1 += ks2 + 4u;
  TFR(13u) TFR(15u) TFR(26u) TFR(6u)   x0 += ks2; x1 += k0 + 5u;
#undef TFR
  *o0 = x0; *o1 = x1;
}

// ---------------- Kernel 1: IoU argmax + proposals + pos flag/count ----------
// APT anchors per thread (lane-striped: i = base + t*K1B, coalesced).
// out[row][0:4] = delta2bbox(anchor, delta); out[row][4] = pos ? best_j+1 : 0;
// out[row][5:7] = 0.  counts[b] += popcount(pos) (one atomic per wave).
__global__ __launch_bounds__(K1B) void k1_classify(
    const float* __restrict__ anchors,
    const float* __restrict__ gt,
    const float* __restrict__ deltas,
    float* __restrict__ out,
    int* __restrict__ counts)
{
  __shared__ float4 gbox[NGT];
  __shared__ float  garea[NGT];
  const int b   = blockIdx.y;
  const int tid = threadIdx.x;

  if (tid < NGT) {
    float4 g = reinterpret_cast<const float4*>(gt)[b * NGT + tid];
    gbox[tid]  = g;
    garea[tid] = fmaxf(g.z - g.x, 0.0f) * fmaxf(g.w - g.y, 0.0f);
  }
  __syncthreads();

  const int base = blockIdx.x * (K1B * APT) + tid;

  float4 a[APT];
  float  areaA[APT], best[APT];
  int    bidx[APT];
#pragma unroll
  for (int t = 0; t < APT; ++t) {
    a[t] = reinterpret_cast<const float4*>(anchors)[base + t * K1B];
    areaA[t] = fmaxf(a[t].z - a[t].x, 0.0f) * fmaxf(a[t].w - a[t].y, 0.0f);
    best[t] = -1.0f;
    bidx[t] = 0;
  }

  // IoU argmax over 64 gt boxes. Expression is FMA-contraction-free =>
  // decisions bit-identical to the fp32 reference. 4 independent chains
  // per iteration hide LDS + precise-div latency.
  for (int j = 0; j < NGT; ++j) {
    const float4 g  = gbox[j];
    const float  ga = garea[j];
#pragma unroll
    for (int t = 0; t < APT; ++t) {
      float yi = fmaxf(a[t].x, g.x);
      float xi = fmaxf(a[t].y, g.y);
      float ya = fminf(a[t].z, g.z);
      float xa = fminf(a[t].w, g.w);
      float inter = fmaxf(ya - yi, 0.0f) * fmaxf(xa - xi, 0.0f);
      float den   = ((areaA[t] + ga) - inter) + 1e-5f;   // union + EPS, exact order
      float iou   = (10000.0f * inter) / den;
      bool upd = iou > best[t];                          // first-max == jnp.argmax
      best[t] = upd ? iou : best[t];
      bidx[t] = upd ? j   : bidx[t];
    }
  }

  int npos = 0;
#pragma unroll
  for (int t = 0; t < APT; ++t) {
    const int i = base + t * K1B;
    const bool pos = best[t] > 5000.0f;

    const float4 d = reinterpret_cast<const float4*>(deltas)[b * NAC + i];
    const float wb = a[t].w - a[t].y, hb = a[t].z - a[t].x;
    const float xc = a[t].y + 0.5f * wb + wb * d.x;
    const float yc = a[t].x + 0.5f * hb + hb * d.y;
    const float w_ = wb * __expf(d.z);
    const float h_ = hb * __expf(d.w);

    float* rowp = out + ((size_t)b * NAC + i) * 8;
    reinterpret_cast<float4*>(rowp)[0] =
        make_float4(yc - 0.5f * h_, xc - 0.5f * w_, yc + 0.5f * h_, xc + 0.5f * w_);
    reinterpret_cast<float4*>(rowp)[1] =
        make_float4(pos ? (float)(bidx[t] + 1) : 0.0f, 0.0f, 0.0f, 0.0f);

    unsigned long long m = __ballot(pos);
    if ((tid & 63) == 0) npos += (int)__popcll(m);
  }
  if ((tid & 63) == 0 && npos)
    atomicAdd(&counts[b], npos);
}

// ---------------- Kernel 2: sparse threefry sampling + bbox2delta -----------
// One thread per row; ~98-99% exit on flag==0 (out[4:8] already zeroed by k1).
// bits[f] = o0^o1 of threefry(kp, 0, f); u = bitcast((bits>>9)|0x3F800000)-1.
__global__ __launch_bounds__(256) void k2_sample(
    const float* __restrict__ anchors,
    const float* __restrict__ gt,
    float* __restrict__ out,
    const int* __restrict__ counts,
    uint32_t kp0, uint32_t kp1)
{
  const int b = blockIdx.y;
  const int i = blockIdx.x * 256 + threadIdx.x;
  const int f = b * NAC + i;
  float* rowp = out + (size_t)f * 8;

  const float flag = rowp[4];
  if (flag == 0.0f) return;          // non-pos row: stays (prop, 0,0,0,0)

  const float th = 128.0f / ((float)counts[b] + 1e-6f);

  uint32_t o0, o1;
  threefry2x32(kp0, kp1, 0u, (uint32_t)f, &o0, &o1);
  const uint32_t bits = o0 ^ o1;
  union { uint32_t u; float fl; } cv;
  cv.u = (bits >> 9) | 0x3F800000u;
  const float rnd = cv.fl - 1.0f;

  float4 r = make_float4(0.0f, 0.0f, 0.0f, 0.0f);
  if (rnd < th) {
    const int j = (int)flag - 1;
    const float4 a = reinterpret_cast<const float4*>(anchors)[i];
    const float4 g = reinterpret_cast<const float4*>(gt)[b * NGT + j];

    const float wr  = a.w - a.y,          hr  = a.z - a.x;
    const float xcr = a.y + 0.5f * wr,    ycr = a.x + 0.5f * hr;
    const float wrc = fmaxf(wr, 1e-5f),   hrc = fmaxf(hr, 1e-5f);
    const float wl  = g.w - g.y,          hl  = g.z - g.x;
    const float xcl = g.y + 0.5f * wl,    ycl = g.x + 0.5f * hl;

    r.x = fminf(fmaxf((xcl - xcr) / wrc, -10.0f), 10.0f);
    r.y = fminf(fmaxf((ycl - ycr) / hrc, -10.0f), 10.0f);
    r.z = fminf(fmaxf(__logf(wl / wrc),  -10.0f), 10.0f);
    r.w = fminf(fmaxf(__logf(hl / hrc),  -10.0f), 10.0f);
  }

  reinterpret_cast<float4*>(rowp)[1] = r;   // selected -> deltas, else zeros
}

extern "C" void kernel_launch(void* const* d_in, const int* in_sizes, int n_in,
                              void* d_out, int out_size, void* d_ws, size_t ws_size,
                              hipStream_t stream)
{
  const float* anchors = (const float*)d_in[0];
  const float* gt      = (const float*)d_in[1];
  const float* deltas  = (const float*)d_in[2];
  float* out  = (float*)d_out;
  int* counts = (int*)d_ws;

  hipMemsetAsync(counts, 0, NB * sizeof(int), stream);

  // kp = jax.random.split(jax.random.key(42))[0] under threefry_partitionable:
  // kp = threefry2x32((0,42), 0, 0), full output pair.
  uint32_t kp0, kp1;
  threefry2x32(0u, 42u, 0u, 0u, &kp0, &kp1);

  dim3 g1(NAC / (K1B * APT), NB);           // (144, 8)
  k1_classify<<<g1, dim3(K1B), 0, stream>>>(anchors, gt, deltas, out, counts);

  dim3 g2(NAC / 256, NB);                   // (576, 8)
  k2_sample<<<g2, dim3(256), 0, stream>>>(anchors, gt, out, counts, kp0, kp1);
}